// Round 5
// baseline (151.036 us; speedup 1.0000x reference)
//
#include <hip/hip_runtime.h>
#include <math.h>

#define NROWS 1000
#define TWO_R_N 2160.0f   // 2*RADIUS*NUM_POINTS
typedef unsigned int uint;
typedef unsigned long long ull;

__device__ __forceinline__ float wsumf(float v){
#pragma unroll
  for(int o=32;o;o>>=1) v += __shfl_xor(v,o,64);
  return v;
}
__device__ __forceinline__ float wmaxf(float v){
#pragma unroll
  for(int o=32;o;o>>=1) v = fmaxf(v,__shfl_xor(v,o,64));
  return v;
}
__device__ __forceinline__ uint wsumu(uint v){
#pragma unroll
  for(int o=32;o;o>>=1) v += (uint)__shfl_xor((int)v,o,64);
  return v;
}

// One block per (batch, prior-group-of-4); wave w handles prior pg*4+w.
// F staged once per block (coalesced), phases after pass 1 are wave-local.
__global__ __launch_bounds__(256,1) void clr_task(const float* __restrict__ feat,
                                                  const float* __restrict__ lab,
                                                  float* __restrict__ ws)
{
  const int b  = blockIdx.x & 63;   // XCD = blockIdx%8 = b%8: all 4 blocks of batch b share an XCD
  const int pg = blockIdx.x >> 6;
  const float* __restrict__ F = feat + (size_t)b*NROWS*78;

  __shared__ __align__(16) float buf[2][4992];  // 64 rows x 78 floats, double-buffered (39.9 KB)
  __shared__ float2 sSP[4][NROWS];              // per-prior (S, r*t)  (32 KB)
  __shared__ float2 sC[NROWS];                  // per-row (c0, c1)    (8 KB)
  __shared__ int selIdx[4][64];

  const int tid = threadIdx.x, wave = tid>>6, lane = tid&63;
  const int rl = lane>>2, q = lane&3;
  const int prior = pg*4 + wave;
  const float* __restrict__ P = lab + ((size_t)b*16 + prior)*78;

  // wave's prior slices in registers
  const float2* P2 = (const float2*)P;
  float2 pv[9];
#pragma unroll
  for(int j=0;j<9;j++) pv[j]=P2[3+q+4*j];       // cols {6+2q+8j, +1}
  const float2 p01=P2[0], p23=P2[1], p45=P2[2];

  float accR=0.f, accT=0.f, accD=0.f, accL=0.f;

  // stage chunk 0 (rows 0..63) directly
  {
    const float4* s4=(const float4*)F;
    float4* d4=(float4*)buf[0];
#pragma unroll
    for(int t=0;t<5;++t){ int e=tid+256*t; if(e<1248) d4[e]=s4[e]; }
  }
  __syncthreads();

  for(int c=0;c<16;++c){
    // prefetch chunk c+1 into registers (loads in flight during compute)
    float4 st[5];
    const int nc=c+1;
    const int n4n = (nc<15)?1248:((nc==15)?780:0);
    const float4* s4=(const float4*)(F+(size_t)nc*4992);
#pragma unroll
    for(int t=0;t<5;++t){ int e=tid+256*t; if(e<n4n) st[t]=s4[e]; }

    // compute chunk c from buf[c&1]; each wave vs its own prior
    const float* bp = buf[c&1];
#pragma unroll
    for(int sub=0;sub<4;++sub){
      int r = c*64 + sub*16 + rl;
      if(r<NROWS){
        const float2* rp2 = (const float2*)(bp + (sub*16+rl)*78);
        float part=0.f;
#pragma unroll
        for(int j=0;j<9;++j){ float2 v=rp2[3+q+4*j]; part += fabsf(v.x-pv[j].x)+fabsf(v.y-pv[j].y); }
        float s1 = part + __shfl_xor(part,1,64);
        float S  = s1   + __shfl_xor(s1,  2,64);
        if(q==0){
          float2 c01=rp2[0], c23=rp2[1], c45=rp2[2];
          float dr3=c23.y-p23.y, dr4=c45.x-p45.x;
          float r2=dr3*dr3+dr4*dr4;
          float t=c45.y-p45.y;
          sSP[wave][r]=make_float2(S, sqrtf(r2)*t);
          if(wave==0) sC[r]=c01;
          accR+=r2; accT+=t*t;
          float dd=S*(1.f/72.f); accD+=dd*dd;
          accL += 1.f-(TWO_R_N-S)/(TWO_R_N+S+1e-9f);
        }
      }
    }
    // write prefetched chunk to the other buffer
    {
      float4* d4=(float4*)buf[nc&1];
#pragma unroll
      for(int t=0;t<5;++t){ int e=tid+256*t; if(e<n4n) d4[e]=st[t]; }
    }
    __syncthreads();
  }

  // ---- wave-local normalizers (only q==0 lanes accumulated; others hold 0) ----
  float R=wsumf(accR), Tt=wsumf(accT), D=wsumf(accD), L=wsumf(accL);
  float Nr=fmaxf(sqrtf(R),1e-12f), Nt=fmaxf(sqrtf(Tt),1e-12f), Nd=fmaxf(sqrtf(D),1e-12f);
  const float inv = 1.f/(Nr*Nt*Nd);
  int k=(int)L; if(k<1)k=1; if(k>64)k=64;   // trunc == astype(int32)

  // ---- wave-local column log-softmax (over the 1000 axis) ----
  float m0=-INFINITY, m1=-INFINITY;
#pragma unroll
  for(int t=0;t<16;++t){ int i=t*64+lane; if(i<NROWS){ float2 v=sC[i]; m0=fmaxf(m0,v.x); m1=fmaxf(m1,v.y);} }
  m0=wmaxf(m0); m1=wmaxf(m1);
  float s0=0.f, s1=0.f;
#pragma unroll
  for(int t=0;t<16;++t){ int i=t*64+lane; if(i<NROWS){ float2 v=sC[i]; s0+=expf(v.x-m0); s1+=expf(v.y-m1);} }
  s0=wsumf(s0); s1=wsumf(s1);
  const float lse0=m0+logf(s0), lse1=m1+logf(s1);

  // ---- per-row cost -> monotone uint keys (16 per lane, row = t*64+lane) ----
  uint key[16];
  const float p0=p01.x, pp1=p01.y;
#pragma unroll
  for(int t=0;t<16;++t){
    int i=t*64+lane; uint kk=0xFFFFFFFFu;   // phantom sorts above all real keys
    if(i<NROWS){
      float2 cc=sC[i]; float2 sp=sSP[wave][i];
      float ls0=cc.x-lse0, ls1=cc.y-lse1;
      float e0=expf(ls0), e1=expf(ls1);
      float focal=(1.f-e0)*(1.f-e0)*ls0*p0+(1.f-e1)*(1.f-e1)*ls1*pp1;
      float prod=sp.y*(sp.x*(1.f/72.f))*inv;
      float cost=3.f*prod*prod+focal;
      uint x=__float_as_uint(cost);
      kk=(x&0x80000000u)?~x:(x|0x80000000u);
    }
    key[t]=kk;
  }

  // ---- k-th smallest: 16x 2-bit MSB-first, one packed wave-reduce per step ----
  uint pref=0u, r=(uint)k;
#pragma unroll
  for(int it=0; it<16; ++it){
    const int shift=30-2*it;
    const uint mh=(it==0)?0u:(0xFFFFFFFFu<<(shift+2));
    uint pc=0u;
#pragma unroll
    for(int t=0;t<16;++t){
      if(((key[t]^pref)&mh)==0u){
        uint bb=(key[t]>>shift)&3u;
        pc += (bb==0u)?1u:((bb==1u)?(1u<<10):((bb==2u)?(1u<<20):0u));
      }
    }
    pc=wsumu(pc);   // counts <=1000 per 10-bit field: no carry
    uint C0=pc&1023u, C1=(pc>>10)&1023u, C2=(pc>>20)&1023u;
    uint bits;
    if(r<=C0)            bits=0u;
    else if(r<=C0+C1)    {bits=1u; r-=C0;}
    else if(r<=C0+C1+C2) {bits=2u; r-=C0+C1;}
    else                 {bits=3u; r-=C0+C1+C2;}
    pref |= bits<<shift;
  }
  const uint T2=pref; uint need=r;   // all < T2, plus first `need` (row order) == T2

  // ---- selection: ballot-prefix compaction, wave-local, no atomics ----
  const ull lmask=(1ull<<lane)-1ull;
  int base=0;
#pragma unroll
  for(int t=0;t<16;++t){
    bool lt = key[t]<T2;
    bool eq = key[t]==T2;
    ull meq=__ballot(eq);
    bool eqs = eq && ((uint)__popcll(meq&lmask) < need);
    uint teq=(uint)__popcll(meq);
    need -= (teq<need?teq:need);
    bool s = lt||eqs;
    ull ms=__ballot(s);
    if(s) selIdx[wave][base+(int)__popcll(ms&lmask)] = t*64+lane;
    base += (int)__popcll(ms);
  }

  // ---- Phase C: losses over the k selected rows, per wave ----
  {
    bool act = lane<k;
    int idx = selIdx[wave][act?lane:0];
    const float2* R2=(const float2*)(F+(size_t)idx*78);
    float2 g01=R2[0], g23=R2[1], g45=R2[2];
    float S = sSP[wave][idx].x;
    float mk = act?1.f:0.f;
    float n2=wsumf(g23.x*g23.x*mk), n3=wsumf(g23.y*g23.y*mk);
    float n4=wsumf(g45.x*g45.x*mk), n5=wsumf(g45.y*g45.y*mk);
    float l2=p23.x, l3=p23.y, l4=p45.x, l5=p45.y;
    float de2=fmaxf(sqrtf(n2+l2*l2),1e-12f);
    float de3=fmaxf(sqrtf(n3+l3*l3),1e-12f);
    float de4=fmaxf(sqrtf(n4+l4*l4),1e-12f);
    float de5=fmaxf(sqrtf(n5+l5*l5),1e-12f);
    float d2=g23.x/de2-l2/de2, d3=g23.y/de3-l3/de3, d4=g45.x/de4-l4/de4, d5=g45.y/de5-l5/de5;
    auto h=[](float d){ float ad=fabsf(d); return ad<1.f ? 0.5f*d*d : ad-0.5f; };
    float sl1 = 0.25f*(h(d2)+h(d3)+h(d4)+h(d5));
    float mm=fmaxf(g01.x,g01.y);
    float lsee=mm+logf(expf(g01.x-mm)+expf(g01.y-mm));
    float logpt=((pp1>p0)?g01.y:g01.x)-lsee;   // tgt=argmax(prior[:2]), first-max -> 0
    float pt=expf(logpt);
    float fl=-(1.f-pt)*(1.f-pt)*logpt;
    float ll=1.f-(TWO_R_N-S)/(TWO_R_N+S+1e-9f);
    float ssl=wsumf(sl1*mk), sll=wsumf(ll*mk), sfl=wsumf(fl*mk);
    if(lane==0){
      float invk=1.f/(float)k;
      float* o = ws + (size_t)(b*16+prior)*3;   // plain stores: no init kernel needed
      o[0]=ssl*invk; o[1]=sll*invk; o[2]=sfl*invk;
    }
  }
}

__global__ __launch_bounds__(256) void clr_finalize(const float* __restrict__ ws,
                                                    float* __restrict__ out)
{
  float a=0.f, bsum=0.f, c=0.f;
  for(int i=threadIdx.x;i<1024;i+=256){
    a    += ws[i*3+0];
    bsum += ws[i*3+1];
    c    += ws[i*3+2];
  }
  a=wsumf(a); bsum=wsumf(bsum); c=wsumf(c);
  __shared__ float r[12];
  int wave=threadIdx.x>>6, lane=threadIdx.x&63;
  if(lane==0){ r[wave*3]=a; r[wave*3+1]=bsum; r[wave*3+2]=c; }
  __syncthreads();
  if(threadIdx.x==0){
    float sa=0,sb=0,sc=0;
    for(int w=0;w<4;w++){sa+=r[w*3];sb+=r[w*3+1];sc+=r[w*3+2];}
    float sl1l=sa*(1.f/1024.f), ll=sb*(1.f/1024.f), fl=sc*(1.f/1024.f);
    // LW_XYTL=0.5, LW_LIOU=2.0, LW_CLS=2.0
    float loss = (sl1l>0.f ? 0.5f*sl1l : 0.f)
               + (ll  >0.f ? 2.0f*ll   : 0.f)
               + (fl  >0.f ? 2.0f*fl   : 0.f);
    out[0]=loss;
  }
}

extern "C" void kernel_launch(void* const* d_in, const int* in_sizes, int n_in,
                              void* d_out, int out_size, void* d_ws, size_t ws_size,
                              hipStream_t stream)
{
  const float* feat = (const float*)d_in[0];   // (64,1000,78) f32
  const float* lab  = (const float*)d_in[1];   // (64,16,78)  f32
  float* ws  = (float*)d_ws;                   // 1024*3 floats, fully overwritten
  float* out = (float*)d_out;
  hipLaunchKernelGGL(clr_task, dim3(256), dim3(256), 0, stream, feat, lab, ws);
  hipLaunchKernelGGL(clr_finalize, dim3(1), dim3(256), 0, stream, ws, out);
}

// Round 6
// 126.452 us; speedup vs baseline: 1.1944x; 1.1944x over previous
//
#include <hip/hip_runtime.h>
#include <math.h>

#define NROWS 1000
#define TWO_R_N 2160.0f   // 2*RADIUS*NUM_POINTS
typedef unsigned int uint;
typedef unsigned long long ull;

__device__ __forceinline__ float wsumf(float v){
#pragma unroll
  for(int o=32;o;o>>=1) v += __shfl_xor(v,o,64);
  return v;
}
__device__ __forceinline__ float wmaxf(float v){
#pragma unroll
  for(int o=32;o;o>>=1) v = fmaxf(v,__shfl_xor(v,o,64));
  return v;
}

// 1024 blocks = 64 batches x 16 priors; co-resident blocks {x,x+256,...} share
// batch b = x&63 -> same F through L1/L2. One barrier; post-work on wave 0 only.
__global__ __launch_bounds__(256,4) void clr_task(const float* __restrict__ feat,
                                                  const float* __restrict__ lab,
                                                  float* __restrict__ ws)
{
  const int b = blockIdx.x & 63;
  const int l = blockIdx.x >> 6;
  const float* __restrict__ F = feat + (size_t)b*NROWS*78;
  const float* __restrict__ P = lab + ((size_t)b*16 + l)*78;

  __shared__ __align__(16) float4 sRow[NROWS];  // (S, r*t, c0, c1)  16 KB
  __shared__ float red[16];
  __shared__ int selIdx[64];

  const int tid=threadIdx.x, wave=tid>>6, lane=tid&63;

  const float2* Pf2 = (const float2*)P;
  const float2 p01=Pf2[0], p23=Pf2[1], p45=Pf2[2];

  // ---- Pass 1: thread-per-row (rows tid+256t), no shuffles, no barriers ----
  const float2* rp[4];
#pragma unroll
  for(int t=0;t<4;++t){
    int r = tid + 256*t;
    rp[t] = (const float2*)(F + (size_t)((r<NROWS)?r:0)*78);
  }
  const bool have3 = (tid+768) < NROWS;
  float acc[4]={0.f,0.f,0.f,0.f};
#pragma unroll 6
  for(int j=0;j<36;++j){
    float2 pj = Pf2[3+j];                  // uniform -> scalarized/broadcast
#pragma unroll
    for(int t=0;t<4;++t){
      float2 v = rp[t][3+j];               // imm-offset global_load_dwordx2
      acc[t] += fabsf(v.x-pj.x) + fabsf(v.y-pj.y);
    }
  }
  float accR=0.f,accT=0.f,accD=0.f,accL=0.f;
#pragma unroll
  for(int t=0;t<4;++t){
    if(t==3 && !have3) break;
    int r = tid + 256*t;
    float2 h0=rp[t][0], h1=rp[t][1], h2=rp[t][2];  // cols (0,1),(2,3),(4,5)
    float S = acc[t];
    float dr3=h1.y-p23.y, dr4=h2.x-p45.x;
    float r2=dr3*dr3+dr4*dr4;
    float tt=h2.y-p45.y;
    sRow[r]=make_float4(S, sqrtf(r2)*tt, h0.x, h0.y);
    accR+=r2; accT+=tt*tt;
    float dd=S*(1.f/72.f); accD+=dd*dd;
    accL += 1.f-(TWO_R_N-S)/(TWO_R_N+S+1e-9f);
  }
  {
    float vR=wsumf(accR), vT=wsumf(accT), vD=wsumf(accD), vL=wsumf(accL);
    if(lane==0){ red[wave*4]=vR; red[wave*4+1]=vT; red[wave*4+2]=vD; red[wave*4+3]=vL; }
  }
  __syncthreads();                         // the only barrier
  if (wave != 0) return;                   // waves 1-3 free their SIMD slots

  // ---- wave-0 tail: normalizers ----
  float R=0.f,T=0.f,D=0.f,L=0.f;
#pragma unroll
  for(int w=0;w<4;w++){ R+=red[w*4]; T+=red[w*4+1]; D+=red[w*4+2]; L+=red[w*4+3]; }
  float Nr=fmaxf(sqrtf(R),1e-12f), Nt=fmaxf(sqrtf(T),1e-12f), Nd=fmaxf(sqrtf(D),1e-12f);
  const float inv = 1.f/(Nr*Nt*Nd);
  int k=(int)L; if(k<1)k=1; if(k>64)k=64;  // trunc == astype(int32)

  // ---- column log-softmax over 1000 rows (wave-local, 3 LDS sweeps) ----
  float m0=-INFINITY, m1=-INFINITY;
#pragma unroll
  for(int t=0;t<16;++t){ int i=t*64+lane; if(i<NROWS){ float4 v=sRow[i]; m0=fmaxf(m0,v.z); m1=fmaxf(m1,v.w);} }
  m0=wmaxf(m0); m1=wmaxf(m1);
  float s0=0.f, s1=0.f;
#pragma unroll
  for(int t=0;t<16;++t){ int i=t*64+lane; if(i<NROWS){ float4 v=sRow[i]; s0+=__expf(v.z-m0); s1+=__expf(v.w-m1);} }
  s0=wsumf(s0); s1=wsumf(s1);
  const float lse0=m0+__logf(s0), lse1=m1+__logf(s1);

  // ---- per-row cost -> monotone keys (16 per lane) ----
  uint key[16];
  const float p0=p01.x, pp1=p01.y;
#pragma unroll
  for(int t=0;t<16;++t){
    int i=t*64+lane; uint kk=0xFFFFFFFFu;  // phantom sorts above everything
    if(i<NROWS){
      float4 v=sRow[i];
      float ls0=v.z-lse0, ls1=v.w-lse1;
      float e0=__expf(ls0), e1=__expf(ls1);
      float focal=(1.f-e0)*(1.f-e0)*ls0*p0 + (1.f-e1)*(1.f-e1)*ls1*pp1;
      float prod=v.y*(v.x*(1.f/72.f))*inv;
      float cost=3.f*prod*prod+focal;
      uint x=__float_as_uint(cost);
      kk=(x&0x80000000u)?~x:(x|0x80000000u);
    }
    key[t]=kk;
  }

  // ---- k-th smallest: 32x 1-bit ballot binary search (no shfl, no barrier) ----
  uint pref=0u, r=(uint)k;
  for(int s=31;s>=0;--s){
    const uint pp=pref>>s;                 // candidate prefix with bit s = 0
    uint cnt=0u;
#pragma unroll
    for(int t=0;t<16;++t) cnt += (uint)__popcll(__ballot((key[t]>>s)==pp));
    if(r>cnt){ r-=cnt; pref|=(1u<<s); }
  }
  const uint T2=pref; uint need=r;         // all <T2 plus first `need` ==T2 (row order)

  // ---- selection: ballot-prefix compaction ----
  const ull lmask=(1ull<<lane)-1ull;
  int base=0;
#pragma unroll
  for(int t=0;t<16;++t){
    bool lt = key[t]<T2;
    bool eq = key[t]==T2;
    ull meq=__ballot(eq);
    bool eqs = eq && ((uint)__popcll(meq&lmask)<need);
    uint teq=(uint)__popcll(meq);
    need -= (teq<need?teq:need);
    bool ssel = lt||eqs;
    ull ms=__ballot(ssel);
    if(ssel) selIdx[base+(int)__popcll(ms&lmask)] = t*64+lane;
    base += (int)__popcll(ms);
  }

  // ---- Phase C ----
  {
    bool act = lane<k;
    int idx = selIdx[act?lane:0];
    const float2* R2=(const float2*)(F+(size_t)idx*78);
    float2 g01=R2[0], g23=R2[1], g45=R2[2];
    float S = sRow[idx].x;
    float mk = act?1.f:0.f;
    float n2=wsumf(g23.x*g23.x*mk), n3=wsumf(g23.y*g23.y*mk);
    float n4=wsumf(g45.x*g45.x*mk), n5=wsumf(g45.y*g45.y*mk);
    float l2=p23.x, l3=p23.y, l4=p45.x, l5=p45.y;
    float de2=fmaxf(sqrtf(n2+l2*l2),1e-12f);
    float de3=fmaxf(sqrtf(n3+l3*l3),1e-12f);
    float de4=fmaxf(sqrtf(n4+l4*l4),1e-12f);
    float de5=fmaxf(sqrtf(n5+l5*l5),1e-12f);
    float d2=g23.x/de2-l2/de2, d3=g23.y/de3-l3/de3, d4=g45.x/de4-l4/de4, d5=g45.y/de5-l5/de5;
    auto h=[](float d){ float ad=fabsf(d); return ad<1.f ? 0.5f*d*d : ad-0.5f; };
    float sl1 = 0.25f*(h(d2)+h(d3)+h(d4)+h(d5));
    float mm=fmaxf(g01.x,g01.y);
    float lsee=mm+__logf(__expf(g01.x-mm)+__expf(g01.y-mm));
    float logpt=((pp1>p0)?g01.y:g01.x)-lsee;   // tgt=argmax(prior[:2]), first-max -> 0
    float pt=__expf(logpt);
    float fl=-(1.f-pt)*(1.f-pt)*logpt;
    float ll=1.f-(TWO_R_N-S)/(TWO_R_N+S+1e-9f);
    float ssl=wsumf(sl1*mk), sll=wsumf(ll*mk), sfl=wsumf(fl*mk);
    if(lane==0){
      float invk=1.f/(float)k;
      float* o = ws + (size_t)(b*16+l)*3;
      o[0]=ssl*invk; o[1]=sll*invk; o[2]=sfl*invk;
    }
  }
}

__global__ __launch_bounds__(256) void clr_finalize(const float* __restrict__ ws,
                                                    float* __restrict__ out)
{
  float a=0.f, bsum=0.f, c=0.f;
  for(int i=threadIdx.x;i<1024;i+=256){
    a    += ws[i*3+0];
    bsum += ws[i*3+1];
    c    += ws[i*3+2];
  }
  a=wsumf(a); bsum=wsumf(bsum); c=wsumf(c);
  __shared__ float r[12];
  int wave=threadIdx.x>>6, lane=threadIdx.x&63;
  if(lane==0){ r[wave*3]=a; r[wave*3+1]=bsum; r[wave*3+2]=c; }
  __syncthreads();
  if(threadIdx.x==0){
    float sa=0,sb=0,sc=0;
    for(int w=0;w<4;w++){sa+=r[w*3];sb+=r[w*3+1];sc+=r[w*3+2];}
    float sl1l=sa*(1.f/1024.f), ll=sb*(1.f/1024.f), fl=sc*(1.f/1024.f);
    // LW_XYTL=0.5, LW_LIOU=2.0, LW_CLS=2.0
    float loss = (sl1l>0.f ? 0.5f*sl1l : 0.f)
               + (ll  >0.f ? 2.0f*ll   : 0.f)
               + (fl  >0.f ? 2.0f*fl   : 0.f);
    out[0]=loss;
  }
}

extern "C" void kernel_launch(void* const* d_in, const int* in_sizes, int n_in,
                              void* d_out, int out_size, void* d_ws, size_t ws_size,
                              hipStream_t stream)
{
  const float* feat = (const float*)d_in[0];   // (64,1000,78) f32
  const float* lab  = (const float*)d_in[1];   // (64,16,78)  f32
  float* ws  = (float*)d_ws;                   // 1024*3 floats, fully overwritten
  float* out = (float*)d_out;
  hipLaunchKernelGGL(clr_task, dim3(1024), dim3(256), 0, stream, feat, lab, ws);
  hipLaunchKernelGGL(clr_finalize, dim3(1), dim3(256), 0, stream, ws, out);
}

// Round 7
// 115.156 us; speedup vs baseline: 1.3116x; 1.0981x over previous
//
#include <hip/hip_runtime.h>
#include <math.h>

#define NROWS 1000
#define TWO_R_N 2160.0f   // 2*RADIUS*NUM_POINTS
#define LSTR 79           // padded LDS row stride (odd -> conflict-free quad reads)
typedef unsigned int uint;
typedef unsigned long long ull;

__device__ __forceinline__ float wsumf(float v){
#pragma unroll
  for(int o=32;o;o>>=1) v += __shfl_xor(v,o,64);
  return v;
}
__device__ __forceinline__ float wmaxf(float v){
#pragma unroll
  for(int o=32;o;o>>=1) v = fmaxf(v,__shfl_xor(v,o,64));
  return v;
}

// 1024 blocks = 64 batches x 16 priors; 4 blocks/CU share batch b = x&63 via L2.
// Pass 1: coalesced float4 staging -> padded LDS -> quad-per-row (conflict-free).
__global__ __launch_bounds__(256,4) void clr_task(const float* __restrict__ feat,
                                                  const float* __restrict__ lab,
                                                  float* __restrict__ ws)
{
  const int b = blockIdx.x & 63;
  const int l = blockIdx.x >> 6;
  const float* __restrict__ F = feat + (size_t)b*NROWS*78;
  const float* __restrict__ P = lab + ((size_t)b*16 + l)*78;

  __shared__ __align__(16) float sBuf[64*LSTR];   // 20224 B, one 64-row chunk (padded)
  __shared__ __align__(16) float4 sRow[NROWS];    // (S, r*t, c0, c1)  16000 B
  __shared__ float red[16];
  __shared__ int selIdx[64];

  const int tid=threadIdx.x, wave=tid>>6, lane=tid&63;
  const int rloc = tid>>2, q = tid&3;             // quad-per-row within chunk

  const float2* Pf2 = (const float2*)P;
  float2 pv[9];
#pragma unroll
  for(int s=0;s<9;++s) pv[s] = Pf2[3 + q + 4*s];  // prior cols {6+2(q+4s), +1}
  const float2 p01=Pf2[0], p23=Pf2[1], p45=Pf2[2];

  float accR=0.f, accT=0.f, accD=0.f, accL=0.f;

  // prefetch chunk 0 (rows 0..63) into registers, fully coalesced float4
  float4 pre[5];
  {
    const float4* src=(const float4*)F;
#pragma unroll
    for(int j2=0;j2<5;++j2){ int idx=tid+256*j2; if(idx<1248) pre[j2]=src[idx]; }
  }

  for(int c=0;c<16;++c){
    const int nf4 = (c<15)?1248:780;              // chunk 15 has 40 rows
    // write prefetched chunk into padded LDS (each float4 = two same-row pairs)
#pragma unroll
    for(int j2=0;j2<5;++j2){
      int idx = tid+256*j2;
      if(idx<nf4){
        int g  = idx*4;
        int r0 = g/78,  cc0 = g  - 78*r0;
        int g2 = g+2;
        int r1 = g2/78, cc1 = g2 - 78*r1;
        float* w0 = sBuf + r0*LSTR + cc0;
        float* w1 = sBuf + r1*LSTR + cc1;
        w0[0]=pre[j2].x; w0[1]=pre[j2].y;
        w1[0]=pre[j2].z; w1[1]=pre[j2].w;
      }
    }
    __syncthreads();                              // chunk visible to all waves
    // issue next chunk's global loads (fly during compute)
    if(c<15){
      const int nn = (c+1<15)?1248:780;
      const float4* src=(const float4*)(F + (size_t)(c+1)*4992);
#pragma unroll
      for(int j2=0;j2<5;++j2){ int idx=tid+256*j2; if(idx<nn) pre[j2]=src[idx]; }
    }
    // compute chunk c: quad-per-row from LDS, conflict-free (odd stride)
    const int rows = (c<15)?64:40;
    if(rloc<rows){
      const float* rp = sBuf + rloc*LSTR;
      float part=0.f;
#pragma unroll
      for(int s=0;s<9;++s){
        int cw = 6 + 2*(q+4*s);
        part += fabsf(rp[cw]-pv[s].x) + fabsf(rp[cw+1]-pv[s].y);
      }
      float s1 = part + __shfl_xor(part,1,64);
      float S  = s1   + __shfl_xor(s1,  2,64);
      if(q==0){
        int r = c*64 + rloc;
        float c0=rp[0], c1=rp[1], f3=rp[3], f4=rp[4], f5=rp[5];
        float dr3=f3-p23.y, dr4=f4-p45.x;
        float r2=dr3*dr3+dr4*dr4;
        float tt=f5-p45.y;
        sRow[r]=make_float4(S, sqrtf(r2)*tt, c0, c1);
        accR+=r2; accT+=tt*tt;
        float dd=S*(1.f/72.f); accD+=dd*dd;
        accL += 1.f-(TWO_R_N-S)/(TWO_R_N+S+1e-9f);
      }
    }
    __syncthreads();                              // all reads done before rewrite
  }

  {
    float vR=wsumf(accR), vT=wsumf(accT), vD=wsumf(accD), vL=wsumf(accL);
    if(lane==0){ red[wave*4]=vR; red[wave*4+1]=vT; red[wave*4+2]=vD; red[wave*4+3]=vL; }
  }
  __syncthreads();
  if (wave != 0) return;                          // waves 1-3 free their SIMD slots

  // ---- wave-0 tail: normalizers ----
  float R=0.f,T=0.f,D=0.f,L=0.f;
#pragma unroll
  for(int w=0;w<4;w++){ R+=red[w*4]; T+=red[w*4+1]; D+=red[w*4+2]; L+=red[w*4+3]; }
  float Nr=fmaxf(sqrtf(R),1e-12f), Nt=fmaxf(sqrtf(T),1e-12f), Nd=fmaxf(sqrtf(D),1e-12f);
  const float inv = 1.f/(Nr*Nt*Nd);
  int k=(int)L; if(k<1)k=1; if(k>64)k=64;         // trunc == astype(int32)

  // ---- column log-softmax over 1000 rows ----
  float m0=-INFINITY, m1=-INFINITY;
#pragma unroll
  for(int t=0;t<16;++t){ int i=t*64+lane; if(i<NROWS){ float4 v=sRow[i]; m0=fmaxf(m0,v.z); m1=fmaxf(m1,v.w);} }
  m0=wmaxf(m0); m1=wmaxf(m1);
  float s0=0.f, s1=0.f;
#pragma unroll
  for(int t=0;t<16;++t){ int i=t*64+lane; if(i<NROWS){ float4 v=sRow[i]; s0+=__expf(v.z-m0); s1+=__expf(v.w-m1);} }
  s0=wsumf(s0); s1=wsumf(s1);
  const float lse0=m0+__logf(s0), lse1=m1+__logf(s1);

  // ---- per-row cost -> monotone keys (16 per lane) ----
  uint key[16];
  const float p0=p01.x, pp1=p01.y;
#pragma unroll
  for(int t=0;t<16;++t){
    int i=t*64+lane; uint kk=0xFFFFFFFFu;         // phantom sorts above everything
    if(i<NROWS){
      float4 v=sRow[i];
      float ls0=v.z-lse0, ls1=v.w-lse1;
      float e0=__expf(ls0), e1=__expf(ls1);
      float focal=(1.f-e0)*(1.f-e0)*ls0*p0 + (1.f-e1)*(1.f-e1)*ls1*pp1;
      float prod=v.y*(v.x*(1.f/72.f))*inv;
      float cost=3.f*prod*prod+focal;
      uint x=__float_as_uint(cost);
      kk=(x&0x80000000u)?~x:(x|0x80000000u);
    }
    key[t]=kk;
  }

  // ---- k-th smallest: 32x 1-bit ballot binary search ----
  uint pref=0u, r=(uint)k;
  for(int s=31;s>=0;--s){
    const uint pp=pref>>s;
    uint cnt=0u;
#pragma unroll
    for(int t=0;t<16;++t) cnt += (uint)__popcll(__ballot((key[t]>>s)==pp));
    if(r>cnt){ r-=cnt; pref|=(1u<<s); }
  }
  const uint T2=pref; uint need=r;                // all <T2 plus first `need` ==T2

  // ---- selection: ballot-prefix compaction ----
  const ull lmask=(1ull<<lane)-1ull;
  int base=0;
#pragma unroll
  for(int t=0;t<16;++t){
    bool lt = key[t]<T2;
    bool eq = key[t]==T2;
    ull meq=__ballot(eq);
    bool eqs = eq && ((uint)__popcll(meq&lmask)<need);
    uint teq=(uint)__popcll(meq);
    need -= (teq<need?teq:need);
    bool ssel = lt||eqs;
    ull ms=__ballot(ssel);
    if(ssel) selIdx[base+(int)__popcll(ms&lmask)] = t*64+lane;
    base += (int)__popcll(ms);
  }

  // ---- Phase C ----
  {
    bool act = lane<k;
    int idx = selIdx[act?lane:0];
    const float2* R2=(const float2*)(F+(size_t)idx*78);
    float2 g01=R2[0], g23=R2[1], g45=R2[2];
    float S = sRow[idx].x;
    float mk = act?1.f:0.f;
    float n2=wsumf(g23.x*g23.x*mk), n3=wsumf(g23.y*g23.y*mk);
    float n4=wsumf(g45.x*g45.x*mk), n5=wsumf(g45.y*g45.y*mk);
    float l2=p23.x, l3=p23.y, l4=p45.x, l5=p45.y;
    float de2=fmaxf(sqrtf(n2+l2*l2),1e-12f);
    float de3=fmaxf(sqrtf(n3+l3*l3),1e-12f);
    float de4=fmaxf(sqrtf(n4+l4*l4),1e-12f);
    float de5=fmaxf(sqrtf(n5+l5*l5),1e-12f);
    float d2=g23.x/de2-l2/de2, d3=g23.y/de3-l3/de3, d4=g45.x/de4-l4/de4, d5=g45.y/de5-l5/de5;
    auto h=[](float d){ float ad=fabsf(d); return ad<1.f ? 0.5f*d*d : ad-0.5f; };
    float sl1 = 0.25f*(h(d2)+h(d3)+h(d4)+h(d5));
    float mm=fmaxf(g01.x,g01.y);
    float lsee=mm+__logf(__expf(g01.x-mm)+__expf(g01.y-mm));
    float logpt=((pp1>p0)?g01.y:g01.x)-lsee;      // tgt=argmax(prior[:2]), first-max -> 0
    float pt=__expf(logpt);
    float fl=-(1.f-pt)*(1.f-pt)*logpt;
    float ll=1.f-(TWO_R_N-S)/(TWO_R_N+S+1e-9f);
    float ssl=wsumf(sl1*mk), sll=wsumf(ll*mk), sfl=wsumf(fl*mk);
    if(lane==0){
      float invk=1.f/(float)k;
      float* o = ws + (size_t)(b*16+l)*3;
      o[0]=ssl*invk; o[1]=sll*invk; o[2]=sfl*invk;
    }
  }
}

__global__ __launch_bounds__(256) void clr_finalize(const float* __restrict__ ws,
                                                    float* __restrict__ out)
{
  float a=0.f, bsum=0.f, c=0.f;
  for(int i=threadIdx.x;i<1024;i+=256){
    a    += ws[i*3+0];
    bsum += ws[i*3+1];
    c    += ws[i*3+2];
  }
  a=wsumf(a); bsum=wsumf(bsum); c=wsumf(c);
  __shared__ float r[12];
  int wave=threadIdx.x>>6, lane=threadIdx.x&63;
  if(lane==0){ r[wave*3]=a; r[wave*3+1]=bsum; r[wave*3+2]=c; }
  __syncthreads();
  if(threadIdx.x==0){
    float sa=0,sb=0,sc=0;
    for(int w=0;w<4;w++){sa+=r[w*3];sb+=r[w*3+1];sc+=r[w*3+2];}
    float sl1l=sa*(1.f/1024.f), ll=sb*(1.f/1024.f), fl=sc*(1.f/1024.f);
    // LW_XYTL=0.5, LW_LIOU=2.0, LW_CLS=2.0
    float loss = (sl1l>0.f ? 0.5f*sl1l : 0.f)
               + (ll  >0.f ? 2.0f*ll   : 0.f)
               + (fl  >0.f ? 2.0f*fl   : 0.f);
    out[0]=loss;
  }
}

extern "C" void kernel_launch(void* const* d_in, const int* in_sizes, int n_in,
                              void* d_out, int out_size, void* d_ws, size_t ws_size,
                              hipStream_t stream)
{
  const float* feat = (const float*)d_in[0];   // (64,1000,78) f32
  const float* lab  = (const float*)d_in[1];   // (64,16,78)  f32
  float* ws  = (float*)d_ws;                   // 1024*3 floats, fully overwritten
  float* out = (float*)d_out;
  hipLaunchKernelGGL(clr_task, dim3(1024), dim3(256), 0, stream, feat, lab, ws);
  hipLaunchKernelGGL(clr_finalize, dim3(1), dim3(256), 0, stream, ws, out);
}